// Round 5
// baseline (352.871 us; speedup 1.0000x reference)
//
#include <hip/hip_runtime.h>
#include <cstdint>
#include <cstddef>

#define AS1 __attribute__((address_space(1)))
#define AS3 __attribute__((address_space(3)))

typedef __bf16 bf16x8 __attribute__((ext_vector_type(8)));
typedef float  f32x4  __attribute__((ext_vector_type(4)));

#define MDIM 16384   // B*S
#define NDIM 1024    // EMBED
#define KDIM 4096    // FFN
#define NQ   8

// ---------------- W2 fp32 -> bf16 (8 elems/thread) ----------------
__global__ __launch_bounds__(256) void conv_w2_kernel(const float* __restrict__ W2,
                                                      __bf16* __restrict__ W2b) {
    size_t base = ((size_t)blockIdx.x * 256 + threadIdx.x) * 8;
    float4 a = *(const float4*)(W2 + base);
    float4 b = *(const float4*)(W2 + base + 4);
    bf16x8 v;
    v[0] = (__bf16)a.x; v[1] = (__bf16)a.y; v[2] = (__bf16)a.z; v[3] = (__bf16)a.w;
    v[4] = (__bf16)b.x; v[5] = (__bf16)b.y; v[6] = (__bf16)b.z; v[7] = (__bf16)b.w;
    *(bf16x8*)(W2b + base) = v;
}

// ============ FUSED: out = relu(q@W1^T+b1) @ W2^T + b2, q = cos(x[:,:8])cos(th)
// Round-5: H is never materialized in HBM. The gemm's A-operand (H) is
// PRODUCED on the fly: wave w owns f-octet w of each BK=64 K-tile; in phase 3
// of tile t it computes H(t+1) for all 256 block rows (lane: rows c*64+l,
// 8 f32 FMA per elem, same accumulation order as the old qh_kernel) and
// ds_writes it lambda-swizzled into the A slices of the next LDS buffer --
// exactly the layout round-3 verified (lambda(row,u)=(row>>3)*32+u*8+(row&7),
// 16B units; write bank pattern lambda&7 = l&7 per 8 lanes = clean).
//  - MFMA/read structure = round-3 (16x16x32, 4 phases, af[4]+bfr[4]/phase;
//    measured 0 bank conflicts; round-4's 32x32 32-row groups 4-way-alias).
//  - W1/b1 tile slices (2KB+32B, L2-hot) arrive via width-4 global_load_lds
//    into per-wave-private LDS (aux), read back as wave-uniform broadcasts.
//  - vmcnt ledger/tile: ph0 issues W1g+b1g+B0(t+1) [4]; ph2 issues B1(t+1)
//    [2]; waits: end-ph1 vmcnt(4) [retire B1(t)], end-ph2 vmcnt(4) [retire
//    W1g/b1g], end-ph3 vmcnt(2)+lgkmcnt(0) [retire B0(t+1), drain H writes].
//    Never 0 in the main loop.
//  - Grid 64x4 = 256 blocks = 1/CU. XCD-affine: xcd=id&7, bn=(id>>3)&3,
//    bm=xcd*8+(id>>5).
#define BM 256
#define BN 256
#define BK 64
#define SLICE 8192   // elems in one 256-row x 32-col bf16 k-slice (16 KiB)

__device__ __forceinline__ void stage_slice(const __bf16* gsrc, __bf16* ldst) {
    __builtin_amdgcn_global_load_lds((AS1 void*)gsrc, (AS3 void*)ldst, 16, 0, 0);
    __builtin_amdgcn_global_load_lds((AS1 void*)(gsrc + (size_t)128 * KDIM),
                                     (AS3 void*)(ldst + 4096), 16, 0, 0);
}

__global__ __launch_bounds__(512, 2) void ffq_fused_kernel(const float* __restrict__ x,
                                                           const float* __restrict__ theta,
                                                           const float* __restrict__ W1,
                                                           const float* __restrict__ b1,
                                                           const __bf16* __restrict__ B,
                                                           const float* __restrict__ bias,
                                                           float* __restrict__ C) {
    __shared__ __align__(16) __bf16 lds[2 * 4 * SLICE];   // 128 KiB
    __shared__ __align__(16) float aux[512];              // per-wave W1 slice (2 KiB)
    __shared__ __align__(16) float auxB[512];             // per-wave b1 slice (dup'd)

    const int tid = threadIdx.x;
    const int w   = tid >> 6;
    const int l   = tid & 63;
    const int id  = blockIdx.x;
    const int xcd = id & 7;
    const int s   = id >> 3;
    const int bn  = s & 3;
    const int bm  = xcd * 8 + (s >> 2);

    const int wm = w >> 2;       // 0..1  (row half)
    const int wn = w & 3;        // 0..3  (col quarter)

    // ---- B staging (source-side permutation for lambda layout), round-3
    const int srow = w * 16 + ((l >> 5) << 3) + (l & 7);
    const int su   = (l >> 3) & 3;
    const __bf16* gB0 = B + (size_t)(bn * BN + srow) * KDIM + su * 8;
    const int w512 = w * 512;

    // ---- fragment read offsets (round-3, measured conflict-free)
    const int ml  = l & 15;
    const int kq  = l >> 4;
    const int lo  = ((ml >> 3) << 8) + ((ml & 7) << 3) + (kq << 6);
    const int axo = wm * 4096 + lo;
    const int bxo = wn * 2048 + lo;

    // ---- prologue: q = cos(x[:, :8]) * cos(theta) for lane rows c*64+l
    float ct[8];
    {
        float4 t0 = *(const float4*)theta;
        float4 t1 = *(const float4*)(theta + 4);
        ct[0] = __cosf(t0.x); ct[1] = __cosf(t0.y); ct[2] = __cosf(t0.z); ct[3] = __cosf(t0.w);
        ct[4] = __cosf(t1.x); ct[5] = __cosf(t1.y); ct[6] = __cosf(t1.z); ct[7] = __cosf(t1.w);
    }
    float q[4][8];
#pragma unroll
    for (int c = 0; c < 4; ++c) {
        const float* xp = x + (size_t)(bm * BM + c * 64 + l) * 1024;
        float4 a = *(const float4*)xp;
        float4 b = *(const float4*)(xp + 4);
        q[c][0] = __cosf(a.x) * ct[0]; q[c][1] = __cosf(a.y) * ct[1];
        q[c][2] = __cosf(a.z) * ct[2]; q[c][3] = __cosf(a.w) * ct[3];
        q[c][4] = __cosf(b.x) * ct[4]; q[c][5] = __cosf(b.y) * ct[5];
        q[c][6] = __cosf(b.z) * ct[6]; q[c][7] = __cosf(b.w) * ct[7];
    }

    // ---- helpers
    auto issueW1 = [&](int tf) {
        // W1 slice: 64 rows x 8 f32 = 256 B for this wave's f-octet, lane l
        // sources dword l; b1: 8 f32 dup'd 8x (lane l sources f = l&7).
        __builtin_amdgcn_global_load_lds((AS1 void*)(W1 + ((size_t)tf * 64 + w * 8) * 8 + l),
                                         (AS3 void*)(aux + w * 64), 4, 0, 0);
        __builtin_amdgcn_global_load_lds((AS1 void*)(b1 + tf * 64 + w * 8 + (l & 7)),
                                         (AS3 void*)(auxB + w * 64), 4, 0, 0);
    };
    auto computeH = [&](__bf16* Abase) {
        const float* w1a = aux + w * 64;
        const float* b1a = auxB + w * 64;
        float h[4][8];
#pragma unroll
        for (int f = 0; f < 8; ++f) {
            f32x4 wa = *(const f32x4*)(w1a + f * 8);
            f32x4 wb = *(const f32x4*)(w1a + f * 8 + 4);
            const float bv = b1a[f];
#pragma unroll
            for (int c = 0; c < 4; ++c) {
                float hv = bv;
                hv += q[c][0] * wa[0]; hv += q[c][1] * wa[1];
                hv += q[c][2] * wa[2]; hv += q[c][3] * wa[3];
                hv += q[c][4] * wb[0]; hv += q[c][5] * wb[1];
                hv += q[c][6] * wb[2]; hv += q[c][7] * wb[3];
                h[c][f] = hv;
            }
        }
        __bf16* An = Abase + (w >> 2) * SLICE;
#pragma unroll
        for (int c = 0; c < 4; ++c) {
            const int r = c * 64 + l;
            bf16x8 o;
#pragma unroll
            for (int f = 0; f < 8; ++f) o[f] = (__bf16)fmaxf(h[c][f], 0.f);
            *(bf16x8*)(An + (((r >> 3) * 32 + (w & 3) * 8 + (r & 7)) << 3)) = o;
        }
    };

    f32x4 acc[8][4] = {};

    // ---- prologue: H(0) -> buf0 A, stage B(0), establish ledger Q=[B1(0)]
    issueW1(0);
    asm volatile("s_waitcnt vmcnt(0)" ::: "memory");
    computeH(lds);
    stage_slice(gB0,      lds + 2 * SLICE + w512);   // B k0 of tile 0
    stage_slice(gB0 + 32, lds + 3 * SLICE + w512);   // B k1 of tile 0
    asm volatile("s_waitcnt vmcnt(2)" ::: "memory");  // B k0 complete
    asm volatile("s_waitcnt lgkmcnt(0)" ::: "memory"); // H writes drained
    __builtin_amdgcn_s_barrier();

#pragma unroll 1
    for (int t = 0; t < KDIM / BK; ++t) {
        const __bf16* bufR = lds + (t & 1) * (4 * SLICE);
        __bf16* bufW = lds + ((t + 1) & 1) * (4 * SLICE);
        const int tf  = (t < KDIM / BK - 1) ? t + 1 : KDIM / BK - 1;  // clamp tail
        const int tnB = tf * BK;

        // -------- phase 0: KS=0, MG=0; issue W1g/b1g + B-k0(t+1) --------
        {
            const __bf16* As = bufR;
            const __bf16* Bs = bufR + 2 * SLICE;
            bf16x8 af[4], bfr[4];
#pragma unroll
            for (int i = 0; i < 4; ++i) af[i]  = *(const bf16x8*)(As + axo + i * 512);
#pragma unroll
            for (int j = 0; j < 4; ++j) bfr[j] = *(const bf16x8*)(Bs + bxo + j * 512);
            issueW1(tf);
            stage_slice(gB0 + tnB, bufW + 2 * SLICE + w512);
            __builtin_amdgcn_s_barrier();
            asm volatile("s_waitcnt lgkmcnt(0)" ::: "memory");
            __builtin_amdgcn_sched_barrier(0);
            __builtin_amdgcn_s_setprio(1);
#pragma unroll
            for (int i = 0; i < 4; ++i)
#pragma unroll
                for (int j = 0; j < 4; ++j)
                    acc[i][j] = __builtin_amdgcn_mfma_f32_16x16x32_bf16(af[i], bfr[j], acc[i][j], 0, 0, 0);
            __builtin_amdgcn_s_setprio(0);
            __builtin_amdgcn_s_barrier();
        }
        // -------- phase 1: KS=0, MG=1; wait B-k1(t) --------
        {
            const __bf16* As = bufR;
            const __bf16* Bs = bufR + 2 * SLICE;
            bf16x8 af[4], bfr[4];
#pragma unroll
            for (int i = 0; i < 4; ++i) af[i]  = *(const bf16x8*)(As + axo + 2048 + i * 512);
#pragma unroll
            for (int j = 0; j < 4; ++j) bfr[j] = *(const bf16x8*)(Bs + bxo + j * 512);
            __builtin_amdgcn_s_barrier();
            asm volatile("s_waitcnt lgkmcnt(0)" ::: "memory");
            __builtin_amdgcn_sched_barrier(0);
            __builtin_amdgcn_s_setprio(1);
#pragma unroll
            for (int i = 0; i < 4; ++i)
#pragma unroll
                for (int j = 0; j < 4; ++j)
                    acc[4 + i][j] = __builtin_amdgcn_mfma_f32_16x16x32_bf16(af[i], bfr[j], acc[4 + i][j], 0, 0, 0);
            __builtin_amdgcn_s_setprio(0);
            asm volatile("s_waitcnt vmcnt(4)" ::: "memory");
            __builtin_amdgcn_s_barrier();
        }
        // -------- phase 2: KS=1, MG=0; issue B-k1(t+1); wait W1g/b1g --------
        {
            const __bf16* As = bufR + SLICE;
            const __bf16* Bs = bufR + 3 * SLICE;
            bf16x8 af[4], bfr[4];
#pragma unroll
            for (int i = 0; i < 4; ++i) af[i]  = *(const bf16x8*)(As + axo + i * 512);
#pragma unroll
            for (int j = 0; j < 4; ++j) bfr[j] = *(const bf16x8*)(Bs + bxo + j * 512);
            stage_slice(gB0 + tnB + 32, bufW + 3 * SLICE + w512);
            __builtin_amdgcn_s_barrier();
            asm volatile("s_waitcnt lgkmcnt(0)" ::: "memory");
            __builtin_amdgcn_sched_barrier(0);
            __builtin_amdgcn_s_setprio(1);
#pragma unroll
            for (int i = 0; i < 4; ++i)
#pragma unroll
                for (int j = 0; j < 4; ++j)
                    acc[i][j] = __builtin_amdgcn_mfma_f32_16x16x32_bf16(af[i], bfr[j], acc[i][j], 0, 0, 0);
            __builtin_amdgcn_s_setprio(0);
            asm volatile("s_waitcnt vmcnt(4)" ::: "memory");
            __builtin_amdgcn_s_barrier();
        }
        // -------- phase 3: KS=1, MG=1; compute H(t+1); wait B-k0(t+1) --------
        {
            const __bf16* As = bufR + SLICE;
            const __bf16* Bs = bufR + 3 * SLICE;
            bf16x8 af[4], bfr[4];
#pragma unroll
            for (int i = 0; i < 4; ++i) af[i]  = *(const bf16x8*)(As + axo + 2048 + i * 512);
#pragma unroll
            for (int j = 0; j < 4; ++j) bfr[j] = *(const bf16x8*)(Bs + bxo + j * 512);
            __builtin_amdgcn_s_barrier();
            asm volatile("s_waitcnt lgkmcnt(0)" ::: "memory");
            __builtin_amdgcn_sched_barrier(0);
            __builtin_amdgcn_s_setprio(1);
#pragma unroll
            for (int i = 0; i < 4; ++i)
#pragma unroll
                for (int j = 0; j < 4; ++j)
                    acc[4 + i][j] = __builtin_amdgcn_mfma_f32_16x16x32_bf16(af[i], bfr[j], acc[4 + i][j], 0, 0, 0);
            __builtin_amdgcn_s_setprio(0);
            computeH(bufW);                               // H(t+1) -> next buf A
            asm volatile("s_waitcnt vmcnt(2)" ::: "memory");
            asm volatile("s_waitcnt lgkmcnt(0)" ::: "memory");
            __builtin_amdgcn_s_barrier();
        }
    }

    // ---- epilogue: 16x16 C/D layout col=lane&15, row=(lane>>4)*4+reg
    const int cm0 = bm * BM + wm * 128;
    const int cn0 = bn * BN + wn * 64;
#pragma unroll
    for (int j = 0; j < 4; ++j) {
        const int col = cn0 + j * 16 + ml;
        const float bv = bias[col];
#pragma unroll
        for (int i = 0; i < 8; ++i) {
            const int row0 = cm0 + i * 16 + kq * 4;
#pragma unroll
            for (int r = 0; r < 4; ++r)
                C[(size_t)(row0 + r) * NDIM + col] = acc[i][j][r] + bv;
        }
    }
}

extern "C" void kernel_launch(void* const* d_in, const int* in_sizes, int n_in,
                              void* d_out, int out_size, void* d_ws, size_t ws_size,
                              hipStream_t stream) {
    const float* x     = (const float*)d_in[0];
    const float* theta = (const float*)d_in[1];
    const float* W1    = (const float*)d_in[2];
    const float* b1    = (const float*)d_in[3];
    const float* W2    = (const float*)d_in[4];
    const float* b2    = (const float*)d_in[5];
    float* out = (float*)d_out;

    __bf16* W2b = (__bf16*)d_ws;   // 8 MiB

    conv_w2_kernel<<<(KDIM * NDIM) / (256 * 8), 256, 0, stream>>>(W2, W2b);
    ffq_fused_kernel<<<(MDIM / BM) * (NDIM / BN), 512, 0, stream>>>(x, theta, W1, b1, W2b, b2, out);
}

// Round 6
// 277.675 us; speedup vs baseline: 1.2708x; 1.2708x over previous
//
#include <hip/hip_runtime.h>
#include <cstdint>
#include <cstddef>

#define AS1 __attribute__((address_space(1)))
#define AS3 __attribute__((address_space(3)))

typedef __bf16 bf16x8 __attribute__((ext_vector_type(8)));
typedef float  f32x4  __attribute__((ext_vector_type(4)));

#define MDIM 16384   // B*S
#define NDIM 1024    // EMBED
#define KDIM 4096    // FFN
#define NQ   8

#define BM 128
#define BN 128
#define BK 64        // bf16 elems per K-chunk (8 x 16B units per row)

// ---------------- W2 fp32 -> bf16 (8 elems/thread) ----------------
__global__ __launch_bounds__(256) void conv_w2_kernel(const float* __restrict__ W2,
                                                      __bf16* __restrict__ W2b) {
    size_t base = ((size_t)blockIdx.x * 256 + threadIdx.x) * 8;
    float4 a = *(const float4*)(W2 + base);
    float4 b = *(const float4*)(W2 + base + 4);
    bf16x8 v;
    v[0] = (__bf16)a.x; v[1] = (__bf16)a.y; v[2] = (__bf16)a.z; v[3] = (__bf16)a.w;
    v[4] = (__bf16)b.x; v[5] = (__bf16)b.y; v[6] = (__bf16)b.z; v[7] = (__bf16)b.w;
    *(bf16x8*)(W2b + base) = v;
}

// ------- H = relu( (cos(x[:, :8]) * cos(theta)) @ W1^T + b1 )  -> bf16 -------
// Round-6: TLP restructure. Old: 512 blocks, per-thread 4096-FMA serial chain
// + 64 stores with only ~8 waves/CU of latency cover -> ~55 us (2.6x over the
// 21 us write floor). New: fc-half moves to blockIdx (grid 2048 = 4x waves),
// QROWS 32->16 halves the per-thread chain again: 1024 FMA + 16 stores/thread.
// Accumulation order per output unchanged -> bit-identical H, absmax stable.
#define QR2 16
__global__ __launch_bounds__(256) void qh_kernel(const float* __restrict__ x,
                                                 const float* __restrict__ theta,
                                                 const float* __restrict__ W1,
                                                 const float* __restrict__ b1,
                                                 __bf16* __restrict__ H) {
    __shared__ __align__(16) float qs[QR2][NQ];
    const int t  = threadIdx.x;
    const int fc = blockIdx.x & 1;             // f-column half (0: 0-2047, 1: 2048-4095)
    const int r0 = (blockIdx.x >> 1) * QR2;    // row group

    if (t < QR2 * NQ) {
        const int qr = t >> 3, qi = t & 7;
        const float xv = x[(size_t)(r0 + qr) * 1024 + qi];
        qs[qr][qi] = __cosf(xv) * __cosf(theta[qi]);
    }
    __syncthreads();

    const int f0 = fc * 2048 + t * 8;
    float w[8][8];
#pragma unroll
    for (int fr = 0; fr < 8; ++fr) {
        float4 a = *(const float4*)(W1 + (size_t)(f0 + fr) * NQ);
        float4 b = *(const float4*)(W1 + (size_t)(f0 + fr) * NQ + 4);
        w[fr][0] = a.x; w[fr][1] = a.y; w[fr][2] = a.z; w[fr][3] = a.w;
        w[fr][4] = b.x; w[fr][5] = b.y; w[fr][6] = b.z; w[fr][7] = b.w;
    }
    float bias[8];
    {
        float4 a = *(const float4*)(b1 + f0);
        float4 b = *(const float4*)(b1 + f0 + 4);
        bias[0] = a.x; bias[1] = a.y; bias[2] = a.z; bias[3] = a.w;
        bias[4] = b.x; bias[5] = b.y; bias[6] = b.z; bias[7] = b.w;
    }
#pragma unroll 1
    for (int r = 0; r < QR2; ++r) {
        const float4 qa = *(const float4*)&qs[r][0];   // LDS broadcast
        const float4 qb = *(const float4*)&qs[r][4];
        float q[8] = { qa.x, qa.y, qa.z, qa.w, qb.x, qb.y, qb.z, qb.w };
        bf16x8 o;
#pragma unroll
        for (int fr = 0; fr < 8; ++fr) {
            float a = bias[fr];
#pragma unroll
            for (int i = 0; i < 8; ++i) a += q[i] * w[fr][i];
            o[fr] = (__bf16)fmaxf(a, 0.f);
        }
        *(bf16x8*)(H + (size_t)(r0 + r) * KDIM + f0) = o;
    }
}

// ---------------- C[M,N] = A[M,K] * B[N,K]^T + bias, bf16 MFMA ----------------
// Round-0 kernel verbatim -- best measured gemm (141.3 us, MfmaUtil 42%,
// 0 bank conflicts). The 256-tile counted-vmcnt rewrites (rounds 1-4) landed
// at 146-159 us; reverting to the proven structure.
// m97 structure: 128x128 block, 4 waves (2x2), each wave 64x64 = 4x4 of
// 16x16x32 MFMA. BK=64, 32 KB LDS, ~3 blocks/CU.
// XCD-affine 1-D grid: xcd=id%8, s=id/8, bn=s%8 (FASTEST), bm=xcd*16+s/8.
// -> all 8 bn-blocks of one bm are on the SAME XCD and adjacent in dispatch
// order, so each 1 MB A-strip is HBM-fetched once and L2-served 8x.
// LDS XOR-swizzle in 16B units: phys(row, u) = u ^ (row & 7). global_load_lds
// writes wave-uniform base + lane*16, so lane i sources logical unit
// (i&7)^(i>>3) via its global address.
__global__ __launch_bounds__(256, 3) void gemm_bt_kernel(const __bf16* __restrict__ A,
                                                         const __bf16* __restrict__ B,
                                                         const float* __restrict__ bias,
                                                         float* __restrict__ C) {
    __shared__ __align__(16) __bf16 Al[BM * BK];
    __shared__ __align__(16) __bf16 Bl[BN * BK];

    const int tid  = threadIdx.x;
    const int wave = tid >> 6;
    const int lane = tid & 63;
    const int id   = blockIdx.x;
    const int xcd  = id & 7;
    const int s    = id >> 3;
    const int bn   = s & 7;
    const int bm   = xcd * 16 + (s >> 3);

    // ---- staging: wave stages rows [wave*32, +32) of A and B, 4 chunks of 8 rows
    const int lr = lane >> 3;            // row within 8-row chunk
    const int ul = (lane & 7) ^ lr;      // logical 16B unit to source (swizzle)
    const __bf16* gA0 = A + (size_t)(bm * BM + wave * 32 + lr) * KDIM + ul * 8;
    const __bf16* gB0 = B + (size_t)(bn * BN + wave * 32 + lr) * KDIM + ul * 8;
    __bf16* lA0 = &Al[(wave * 32) * BK];
    __bf16* lB0 = &Bl[(wave * 32) * BK];

    // ---- fragment indices (16x16x32: lane holds [m=lane&15][k=(lane>>4)*8+j])
    const int ml = lane & 15;
    const int kq = lane >> 4;            // 0..3
    const int sw = lane & 7;             // row & 7 for fragment rows
    const int wm = (wave & 1) * 64;
    const int wn = (wave >> 1) * 64;

    f32x4 acc[4][4] = {};

    for (int kt = 0; kt < KDIM; kt += BK) {
        __syncthreads();   // previous tile's reads done before overwrite
#pragma unroll
        for (int c = 0; c < 4; ++c) {
            __builtin_amdgcn_global_load_lds((AS1 void*)(gA0 + (size_t)c * 8 * KDIM + kt),
                                             (AS3 void*)(lA0 + c * 8 * BK), 16, 0, 0);
            __builtin_amdgcn_global_load_lds((AS1 void*)(gB0 + (size_t)c * 8 * KDIM + kt),
                                             (AS3 void*)(lB0 + c * 8 * BK), 16, 0, 0);
        }
        __syncthreads();   // drains vmcnt -> tiles complete
#pragma unroll
        for (int st = 0; st < 2; ++st) {  // 2 k-steps of 32
            const int u = ((st * 4 + kq) ^ sw) * 8;
            bf16x8 afrag[4], bfrag[4];
#pragma unroll
            for (int i = 0; i < 4; ++i) {
                afrag[i] = *(const bf16x8*)&Al[(wm + i * 16 + ml) * BK + u];
                bfrag[i] = *(const bf16x8*)&Bl[(wn + i * 16 + ml) * BK + u];
            }
#pragma unroll
            for (int i = 0; i < 4; ++i)
#pragma unroll
                for (int j = 0; j < 4; ++j)
                    acc[i][j] = __builtin_amdgcn_mfma_f32_16x16x32_bf16(afrag[i], bfrag[j], acc[i][j], 0, 0, 0);
        }
    }

    // ---- epilogue: 16x16 C/D layout col=lane&15, row=(lane>>4)*4+reg
    const int cm0 = bm * BM + wm;
    const int cn0 = bn * BN + wn;
#pragma unroll
    for (int j = 0; j < 4; ++j) {
        const int col = cn0 + j * 16 + ml;
        const float bv = bias[col];
#pragma unroll
        for (int i = 0; i < 4; ++i) {
            const int row0 = cm0 + i * 16 + kq * 4;
#pragma unroll
            for (int r = 0; r < 4; ++r)
                C[(size_t)(row0 + r) * NDIM + col] = acc[i][j][r] + bv;
        }
    }
}

extern "C" void kernel_launch(void* const* d_in, const int* in_sizes, int n_in,
                              void* d_out, int out_size, void* d_ws, size_t ws_size,
                              hipStream_t stream) {
    const float* x     = (const float*)d_in[0];
    const float* theta = (const float*)d_in[1];
    const float* W1    = (const float*)d_in[2];
    const float* b1    = (const float*)d_in[3];
    const float* W2    = (const float*)d_in[4];
    const float* b2    = (const float*)d_in[5];
    float* out = (float*)d_out;

    __bf16* H   = (__bf16*)d_ws;                                    // 128 MiB
    __bf16* W2b = (__bf16*)((char*)d_ws + (size_t)MDIM * KDIM * 2); // + 8 MiB

    conv_w2_kernel<<<(KDIM * NDIM) / (256 * 8), 256, 0, stream>>>(W2, W2b);
    qh_kernel<<<(MDIM / QR2) * 2, 256, 0, stream>>>(x, theta, W1, b1, H);
    gemm_bt_kernel<<<(MDIM / BM) * (NDIM / BN), 256, 0, stream>>>(H, W2b, b2, out);
}